// Round 2
// baseline (893.301 us; speedup 1.0000x reference)
//
#include <hip/hip_runtime.h>

// LinearTrajectoryAttention, restructured:
//   Qphi = phi(query @ Wq^T + bq)                  [16][16][64]
//   w[b,h,t] = Qphi[b,h,:] . phi(key_t @ Wk^T + bk)[h]   (fused into K-proj epilogue)
//   den[b,h] = sum_t w ;  S[b,h,:] = sum_t w * value_t
//   pre[b,h*64+e] = (Wv[h*64+e,:].S + den*bv) / (den + 1e-6)
//   out = pre @ Wo^T + bo
// R2: kproj rebuilt — pitch-40 LDS for BOTH tiles (conflict-free ds_read_b128),
// full reg-staging, raw s_barrier (no vmcnt drain), 2-deep prefetch,
// v_cvt_pk_bf16_f32 conversion, XCD-bijective block swizzle for A L2-reuse.

typedef __attribute__((ext_vector_type(8))) short  bf16x8;
typedef __attribute__((ext_vector_type(4))) short  bf16x4;
typedef __attribute__((ext_vector_type(4))) float  f32x4;

// workspace layout (bytes)
#define WS_QPHI 0u          // [16][16][64] f32      = 65536
#define WS_PRE  65536u      // [16][1024]  f32       = 65536
#define WS_S    131072u     // [16][16][1024] f32    = 1048576
#define WS_WKB  1179648u    // [1024][1024] bf16     = 2097152
#define WS_W    3276800u    // [16][16][8192] f32    = 8388608  (total ~11.7 MB)

__device__ __forceinline__ unsigned short f2bf(float f) {
  union { float f; unsigned u; } c; c.f = f;
  unsigned u = c.u;
  return (unsigned short)((u + 0x7fffu + ((u >> 16) & 1u)) >> 16);  // RNE
}

__device__ __forceinline__ unsigned cvt_pk_bf16(float lo, float hi) {
  unsigned r;
  asm("v_cvt_pk_bf16_f32 %0, %1, %2" : "=v"(r) : "v"(lo), "v"(hi));
  return r;
}

__device__ __forceinline__ uint4 pack_bf16x8(f32x4 x, f32x4 y) {
  uint4 r;
  r.x = cvt_pk_bf16(x[0], x[1]); r.y = cvt_pk_bf16(x[2], x[3]);
  r.z = cvt_pk_bf16(y[0], y[1]); r.w = cvt_pk_bf16(y[2], y[3]);
  return r;
}

// ---- Wk fp32 -> bf16 ----------------------------------------------------
__global__ void k_convert_wk(const float* __restrict__ Wk, unsigned short* __restrict__ Wkb) {
  int i = blockIdx.x * 256 + threadIdx.x;     // 262144 float4s
  f32x4 v = ((const f32x4*)Wk)[i];
  bf16x4 o;
  o[0] = (short)f2bf(v[0]); o[1] = (short)f2bf(v[1]);
  o[2] = (short)f2bf(v[2]); o[3] = (short)f2bf(v[3]);
  ((bf16x4*)Wkb)[i] = o;
}

// ---- Q projection + feature map ----------------------------------------
__global__ void k_qproj(const float* __restrict__ q, const float* __restrict__ Wq,
                        const float* __restrict__ bq, float* __restrict__ Qphi) {
  int b = blockIdx.x, h = blockIdx.y, d = threadIdx.x;  // block = 64
  const f32x4* qr = (const f32x4*)(q + b * 1024);
  const f32x4* wr = (const f32x4*)(Wq + (size_t)(h * 64 + d) * 1024);
  float s = bq[h * 64 + d];
  for (int i = 0; i < 256; ++i) {
    f32x4 a = qr[i], ww = wr[i];
    s += a[0]*ww[0] + a[1]*ww[1] + a[2]*ww[2] + a[3]*ww[3];
  }
  s = s > 0.f ? s + 1.f : __expf(s);  // elu(x)+1
  Qphi[(b * 16 + h) * 64 + d] = s;
}

// ---- K projection GEMM (BM=128, BN=256=4 heads, BK=32) + fused w epilogue
// Reg-staged A (fp32->bf16 cvt_pk) and B; pitch-40 LDS (conflict-free);
// raw barriers; 2-deep prefetch.
__global__ __launch_bounds__(512)
void k_kproj(const float* __restrict__ key, const unsigned short* __restrict__ Wkb,
             const float* __restrict__ bk, const float* __restrict__ Qphi,
             float* __restrict__ w) {
  __shared__ __align__(16) unsigned short sA[2][128 * 40];  // 2 x 10240 B
  __shared__ __align__(16) unsigned short sB[2][256 * 40];  // 2 x 20480 B

  // XCD-bijective swizzle: the 4 np-sharers of each mb land on the same XCD.
  const int bid  = blockIdx.x + (blockIdx.y << 2);          // 0..4095
  const int work = ((bid & 7) << 9) | (bid >> 3);           // xcd*512 + idx
  const int np   = work & 3;
  const int mb   = work >> 2;
  const int b    = mb >> 6;
  const int mrow = (mb & 63) << 7;
  const int tid  = threadIdx.x;
  const int lane = tid & 63;
  const int wv   = tid >> 6;                   // 8 waves, 2 (rows) x 4 (cols)
  const int wr   = wv >> 2;
  const int wc   = wv & 3;
  const int n0   = np << 8;
  const int h    = (np << 2) | wc;             // this wave's head
  const int l15  = lane & 15;
  const int lk   = (lane >> 4) << 3;           // k-offset 0,8,16,24 shorts

  // A staging map: thread -> row ar = tid/4, 8 floats at col (tid&3)*8
  const int ar = tid >> 2, aq = tid & 3;
  const float* Ag = key + ((size_t)((b << 13) + mrow + ar)) * 1024 + aq * 8;
  const int sAoff = ar * 40 + aq * 8;

  // B staging map: thread -> rows br and br+128, 8 shorts at col (tid&3)*8
  const int br = tid >> 2, bq = tid & 3;
  const unsigned short* Bg = Wkb + ((size_t)(n0 + br)) * 1024 + bq * 8;
  const int sBoff = br * 40 + bq * 8;          // second chunk: +128*40

  f32x4 acc[4][4];
  #pragma unroll
  for (int i = 0; i < 4; ++i)
    #pragma unroll
    for (int j = 0; j < 4; ++j) acc[i][j] = (f32x4)0.f;

  float qreg[4];
  #pragma unroll
  for (int ni = 0; ni < 4; ++ni)
    qreg[ni] = Qphi[((b << 4) + h) * 64 + ni * 16 + l15];

  // ---- prologue: load tiles 0,1 to regs; write tile 0 to LDS[0]
  f32x4  a00 = *(const f32x4*)(Ag);
  f32x4  a01 = *(const f32x4*)(Ag + 4);
  bf16x8 b00 = *(const bf16x8*)(Bg);
  bf16x8 b01 = *(const bf16x8*)(Bg + 128 * 1024);
  f32x4  a10 = *(const f32x4*)(Ag + 32);
  f32x4  a11 = *(const f32x4*)(Ag + 36);
  bf16x8 b10 = *(const bf16x8*)(Bg + 32);
  bf16x8 b11 = *(const bf16x8*)(Bg + 128 * 1024 + 32);
  *(uint4*)&sA[0][sAoff] = pack_bf16x8(a00, a01);
  *(bf16x8*)&sB[0][sBoff] = b00;
  *(bf16x8*)&sB[0][sBoff + 128 * 40] = b01;
  asm volatile("s_waitcnt lgkmcnt(0)" ::: "memory");
  __builtin_amdgcn_s_barrier();
  asm volatile("" ::: "memory");

  #pragma unroll 1
  for (int t = 0; t < 32; t += 2) {
    // ======== even step: read LDS[0]; issue tile t+2 -> slot0; write tile t+1 -> LDS[1]
    if (t < 30) {
      const float* Ap = Ag + (t + 2) * 32;
      a00 = *(const f32x4*)(Ap);
      a01 = *(const f32x4*)(Ap + 4);
      const unsigned short* Bp = Bg + (t + 2) * 32;
      b00 = *(const bf16x8*)(Bp);
      b01 = *(const bf16x8*)(Bp + 128 * 1024);
    }
    {
      bf16x8 af[4], bfr[4];
      #pragma unroll
      for (int mi = 0; mi < 4; ++mi)
        af[mi] = *(const bf16x8*)&sA[0][((wr << 6) + mi * 16 + l15) * 40 + lk];
      #pragma unroll
      for (int ni = 0; ni < 4; ++ni)
        bfr[ni] = *(const bf16x8*)&sB[0][((wc << 6) + ni * 16 + l15) * 40 + lk];
      #pragma unroll
      for (int mi = 0; mi < 4; ++mi)
        #pragma unroll
        for (int ni = 0; ni < 4; ++ni)
          acc[mi][ni] = __builtin_amdgcn_mfma_f32_16x16x32_bf16(af[mi], bfr[ni], acc[mi][ni], 0, 0, 0);
    }
    *(uint4*)&sA[1][sAoff] = pack_bf16x8(a10, a11);   // tile t+1
    *(bf16x8*)&sB[1][sBoff] = b10;
    *(bf16x8*)&sB[1][sBoff + 128 * 40] = b11;
    asm volatile("s_waitcnt lgkmcnt(0)" ::: "memory");
    __builtin_amdgcn_s_barrier();
    asm volatile("" ::: "memory");
    __builtin_amdgcn_sched_barrier(0);

    // ======== odd step: read LDS[1]; issue tile t+3 -> slot1; write tile t+2 -> LDS[0]
    if (t < 29) {
      const float* Ap = Ag + (t + 3) * 32;
      a10 = *(const f32x4*)(Ap);
      a11 = *(const f32x4*)(Ap + 4);
      const unsigned short* Bp = Bg + (t + 3) * 32;
      b10 = *(const bf16x8*)(Bp);
      b11 = *(const bf16x8*)(Bp + 128 * 1024);
    }
    {
      bf16x8 af[4], bfr[4];
      #pragma unroll
      for (int mi = 0; mi < 4; ++mi)
        af[mi] = *(const bf16x8*)&sA[1][((wr << 6) + mi * 16 + l15) * 40 + lk];
      #pragma unroll
      for (int ni = 0; ni < 4; ++ni)
        bfr[ni] = *(const bf16x8*)&sB[1][((wc << 6) + ni * 16 + l15) * 40 + lk];
      #pragma unroll
      for (int mi = 0; mi < 4; ++mi)
        #pragma unroll
        for (int ni = 0; ni < 4; ++ni)
          acc[mi][ni] = __builtin_amdgcn_mfma_f32_16x16x32_bf16(af[mi], bfr[ni], acc[mi][ni], 0, 0, 0);
    }
    if (t < 30) {                                      // tile t+2
      *(uint4*)&sA[0][sAoff] = pack_bf16x8(a00, a01);
      *(bf16x8*)&sB[0][sBoff] = b00;
      *(bf16x8*)&sB[0][sBoff + 128 * 40] = b01;
    }
    asm volatile("s_waitcnt lgkmcnt(0)" ::: "memory");
    __builtin_amdgcn_s_barrier();
    asm volatile("" ::: "memory");
    __builtin_amdgcn_sched_barrier(0);
  }

  // epilogue: bias + phi + dot with Qphi -> w[b,h,t]
  float bias[4];
  #pragma unroll
  for (int ni = 0; ni < 4; ++ni) bias[ni] = bk[n0 + (wc << 6) + ni * 16 + l15];

  #pragma unroll
  for (int mi = 0; mi < 4; ++mi) {
    float wa[4];
    #pragma unroll
    for (int r = 0; r < 4; ++r) {
      float s = 0.f;
      #pragma unroll
      for (int ni = 0; ni < 4; ++ni) {
        float x = acc[mi][ni][r] + bias[ni];
        x = x > 0.f ? x + 1.f : __expf(x);     // phi
        s += x * qreg[ni];
      }
      wa[r] = s;
    }
    #pragma unroll
    for (int m = 1; m < 16; m <<= 1)
      #pragma unroll
      for (int r = 0; r < 4; ++r) wa[r] += __shfl_xor(wa[r], m, 64);
    if (l15 == 0) {
      const int rg = lane >> 4;
      #pragma unroll
      for (int r = 0; r < 4; ++r) {
        int trow = mrow + (wr << 6) + mi * 16 + (rg << 2) + r;
        w[(((size_t)((b << 4) + h)) << 13) + trow] = wa[r];
      }
    }
  }
}

// ---- S[b,h,:] = sum_t w * value_t  (fp32, streaming) --------------------
__global__ __launch_bounds__(256)
void k_sgemm(const float* __restrict__ value, const float* __restrict__ w,
             float* __restrict__ S) {
  __shared__ float wl[16 * 128];
  const int b = blockIdx.x, tc = blockIdx.y;   // 16 x 64
  const int t0 = tc << 7;
  const int tid = threadIdx.x;
  for (int i = tid; i < 16 * 128; i += 256)
    wl[i] = w[(((size_t)(b * 16 + (i >> 7))) << 13) + t0 + (i & 127)];
  __syncthreads();
  f32x4 acc[16];
  #pragma unroll
  for (int h = 0; h < 16; ++h) acc[h] = (f32x4)0.f;
  const f32x4* vb = (const f32x4*)(value + ((size_t)(b << 13) + t0) * 1024) + tid;
  #pragma unroll 4
  for (int t = 0; t < 128; ++t) {
    f32x4 x = vb[t << 8];
    #pragma unroll
    for (int h = 0; h < 16; ++h)
      acc[h] += x * wl[(h << 7) + t];
  }
  #pragma unroll
  for (int h = 0; h < 16; ++h) {
    float* sp = S + ((b << 4) + h) * 1024 + (tid << 2);
    atomicAdd(sp + 0, acc[h][0]); atomicAdd(sp + 1, acc[h][1]);
    atomicAdd(sp + 2, acc[h][2]); atomicAdd(sp + 3, acc[h][3]);
  }
}

// ---- den + num + divide --------------------------------------------------
__global__ void k_numden(const float* __restrict__ w, const float* __restrict__ S,
                         const float* __restrict__ Wv, const float* __restrict__ bv,
                         float* __restrict__ pre) {
  const int b = blockIdx.x, h = blockIdx.y, e = threadIdx.x;  // block = 64
  const float* wb = w + (((size_t)(b * 16 + h)) << 13);
  float dsum = 0.f;
  for (int i = 0; i < 128; ++i) dsum += wb[i * 64 + e];
  #pragma unroll
  for (int m = 1; m < 64; m <<= 1) dsum += __shfl_xor(dsum, m, 64);
  const f32x4* sr  = (const f32x4*)(S + (b * 16 + h) * 1024);
  const f32x4* wvr = (const f32x4*)(Wv + (size_t)(h * 64 + e) * 1024);
  float ns = 0.f;
  for (int i = 0; i < 256; ++i) {
    f32x4 a = sr[i], c = wvr[i];
    ns += a[0]*c[0] + a[1]*c[1] + a[2]*c[2] + a[3]*c[3];
  }
  ns += dsum * bv[h * 64 + e];
  pre[b * 1024 + h * 64 + e] = ns / (dsum + 1e-6f);
}

// ---- output projection ---------------------------------------------------
__global__ __launch_bounds__(256)
void k_outproj(const float* __restrict__ pre, const float* __restrict__ Wo,
               const float* __restrict__ bo, float* __restrict__ out) {
  __shared__ float pl[1024];
  const int b = blockIdx.x, ch = blockIdx.y;   // 16 x 4
  const int tid = threadIdx.x, lane = tid & 63, wv = tid >> 6;
  for (int i = tid; i < 1024; i += 256) pl[i] = pre[b * 1024 + i];
  __syncthreads();
  for (int oi = 0; oi < 64; ++oi) {
    int o = (ch << 8) + (wv << 6) + oi;
    const f32x4* wrow = (const f32x4*)(Wo + (size_t)o * 1024);
    float s = 0.f;
    #pragma unroll
    for (int j = 0; j < 4; ++j) {
      f32x4 v = wrow[lane * 4 + j];
      f32x4 p = *(const f32x4*)&pl[(lane * 4 + j) * 4];
      s += v[0]*p[0] + v[1]*p[1] + v[2]*p[2] + v[3]*p[3];
    }
    #pragma unroll
    for (int m = 1; m < 64; m <<= 1) s += __shfl_xor(s, m, 64);
    if (lane == 0) out[b * 1024 + o] = s + bo[o];
  }
}

extern "C" void kernel_launch(void* const* d_in, const int* in_sizes, int n_in,
                              void* d_out, int out_size, void* d_ws, size_t ws_size,
                              hipStream_t stream) {
  const float* query = (const float*)d_in[0];
  const float* key   = (const float*)d_in[1];
  const float* value = (const float*)d_in[2];
  const float* Wq    = (const float*)d_in[3];
  const float* bq    = (const float*)d_in[4];
  const float* Wk    = (const float*)d_in[5];
  const float* bk    = (const float*)d_in[6];
  const float* Wv    = (const float*)d_in[7];
  const float* bv    = (const float*)d_in[8];
  const float* Wo    = (const float*)d_in[9];
  const float* bo    = (const float*)d_in[10];
  float* out = (float*)d_out;
  char* ws = (char*)d_ws;
  float*          Qphi = (float*)(ws + WS_QPHI);
  float*          pre  = (float*)(ws + WS_PRE);
  float*          S    = (float*)(ws + WS_S);
  unsigned short* Wkb  = (unsigned short*)(ws + WS_WKB);
  float*          w    = (float*)(ws + WS_W);

  hipMemsetAsync(S, 0, 16 * 16 * 1024 * sizeof(float), stream);
  k_convert_wk<<<1024, 256, 0, stream>>>(Wk, Wkb);
  k_qproj<<<dim3(16, 16), 64, 0, stream>>>(query, Wq, bq, Qphi);
  k_kproj<<<dim3(4, 1024), 512, 0, stream>>>(key, Wkb, bk, Qphi, w);
  k_sgemm<<<dim3(16, 64), 256, 0, stream>>>(value, w, S);
  k_numden<<<dim3(16, 16), 64, 0, stream>>>(w, S, Wv, bv, pre);
  k_outproj<<<dim3(16, 4), 256, 0, stream>>>(pre, Wo, bo, out);
}

// Round 3
// 725.600 us; speedup vs baseline: 1.2311x; 1.2311x over previous
//
#include <hip/hip_runtime.h>

// LinearTrajectoryAttention, restructured:
//   Qphi = phi(query @ Wq^T + bq)                  [16][16][64]
//   w[b,h,t] = Qphi[b,h,:] . phi(key_t @ Wk^T + bk)[h]   (fused into K-proj epilogue)
//   den[b,h] = sum_t w ;  S[b,h,:] = sum_t w * value_t
//   pre[b,h*64+e] = (Wv[h*64+e,:].S + den*bv) / (den + 1e-6)
//   out = pre @ Wo^T + bo
// R3: R1 structure (global_load_lds B, __syncthreads, 53KB LDS = 2 blocks/CU)
//   + XCD-bijective swizzle (R2-verified: FETCH 1.07GB -> 412MB)
//   + sB chunk-XOR swizzle via PRE-SWIZZLED GLOBAL SOURCE (rule #21):
//     DMA dest stays linear; source chunk ^= (lane>>3)&3; read chunk ^= (l15>>1)&3.
//     Removes the 8-way bank conflict on sB ds_read_b128 (R1's 4.2e7 cycles).
//   + k_sgemm tc 64->32 (halves device-scope atomics).

typedef __attribute__((ext_vector_type(8))) short  bf16x8;
typedef __attribute__((ext_vector_type(4))) short  bf16x4;
typedef __attribute__((ext_vector_type(4))) float  f32x4;

// workspace layout (bytes)
#define WS_QPHI 0u          // [16][16][64] f32      = 65536
#define WS_PRE  65536u      // [16][1024]  f32       = 65536
#define WS_S    131072u     // [16][16][1024] f32    = 1048576
#define WS_WKB  1179648u    // [1024][1024] bf16     = 2097152
#define WS_W    3276800u    // [16][16][8192] f32    = 8388608  (total ~11.7 MB)

__device__ __forceinline__ unsigned short f2bf(float f) {
  union { float f; unsigned u; } c; c.f = f;
  unsigned u = c.u;
  return (unsigned short)((u + 0x7fffu + ((u >> 16) & 1u)) >> 16);  // RNE
}

__device__ __forceinline__ void gload_lds16(const void* g, void* l) {
  __builtin_amdgcn_global_load_lds((const __attribute__((address_space(1))) void*)g,
                                   (__attribute__((address_space(3))) void*)l, 16, 0, 0);
}

// ---- Wk fp32 -> bf16 ----------------------------------------------------
__global__ void k_convert_wk(const float* __restrict__ Wk, unsigned short* __restrict__ Wkb) {
  int i = blockIdx.x * 256 + threadIdx.x;     // 262144 float4s
  f32x4 v = ((const f32x4*)Wk)[i];
  bf16x4 o;
  o[0] = (short)f2bf(v[0]); o[1] = (short)f2bf(v[1]);
  o[2] = (short)f2bf(v[2]); o[3] = (short)f2bf(v[3]);
  ((bf16x4*)Wkb)[i] = o;
}

// ---- Q projection + feature map ----------------------------------------
__global__ void k_qproj(const float* __restrict__ q, const float* __restrict__ Wq,
                        const float* __restrict__ bq, float* __restrict__ Qphi) {
  int b = blockIdx.x, h = blockIdx.y, d = threadIdx.x;  // block = 64
  const f32x4* qr = (const f32x4*)(q + b * 1024);
  const f32x4* wr = (const f32x4*)(Wq + (size_t)(h * 64 + d) * 1024);
  float s = bq[h * 64 + d];
  for (int i = 0; i < 256; ++i) {
    f32x4 a = qr[i], ww = wr[i];
    s += a[0]*ww[0] + a[1]*ww[1] + a[2]*ww[2] + a[3]*ww[3];
  }
  s = s > 0.f ? s + 1.f : __expf(s);  // elu(x)+1
  Qphi[(b * 16 + h) * 64 + d] = s;
}

// ---- K projection GEMM (BM=128, BN=256=4 heads, BK=32) + fused w epilogue
__global__ __launch_bounds__(512)
void k_kproj(const float* __restrict__ key, const unsigned short* __restrict__ Wkb,
             const float* __restrict__ bk, const float* __restrict__ Qphi,
             float* __restrict__ w) {
  __shared__ unsigned short sA[2][128 * 40];   // padded pitch 40 shorts -> conflict-free
  __shared__ unsigned short sB[2][256 * 32];   // linear dest (DMA), chunk-XOR content

  // XCD-bijective swizzle: 4 np-sharers of each mb on the same XCD; A rows
  // partitioned per-XCD (4096 blocks % 8 == 0 -> bijective).
  const int bid  = blockIdx.x + (blockIdx.y << 2);          // 0..4095
  const int work = ((bid & 7) << 9) | (bid >> 3);           // xcd*512 + idx
  const int np   = work & 3;
  const int mb   = work >> 2;
  const int b    = mb >> 6;
  const int mrow = (mb & 63) << 7;
  const int tid  = threadIdx.x;
  const int lane = tid & 63;
  const int wv   = tid >> 6;                   // 8 waves, 2 (rows) x 4 (cols)
  const int wr   = wv >> 2;
  const int wc   = wv & 3;
  const int n0   = np << 8;
  const int h    = (np << 2) | wc;             // this wave's head
  const int l15  = lane & 15;
  const int lk   = (lane >> 4) << 3;           // k-offset 0,8,16,24 shorts (sA)

  // A staging map: thread -> (row = tid/4, 8 floats at col (tid&3)*8)
  const int ar = tid >> 2, aq = tid & 3;
  const float* Ab = key + ((size_t)((b << 13) + mrow + ar)) * 1024 + aq * 8;
  const int sAoff = ar * 40 + aq * 8;

  // B staging (global_load_lds, 2x16B per lane). Source chunk pre-swizzled:
  // LDS (row, k') must hold global (row, k' ^ ((row>>1)&3)). With dest lane l
  // -> row=(wv<<5)+(l>>2), k'=l&3, the XOR term is (l>>3)&3 for both calls.
  const int bsw = ((lane & 3) ^ ((lane >> 3) & 3)) << 3;    // shorts
  const unsigned short* Bb = Wkb + ((size_t)(n0 + (wv << 5) + (lane >> 2))) * 1024 + bsw;

  f32x4 acc[4][4];
  #pragma unroll
  for (int i = 0; i < 4; ++i)
    #pragma unroll
    for (int j = 0; j < 4; ++j) acc[i][j] = (f32x4)0.f;

  float qreg[4];
  #pragma unroll
  for (int ni = 0; ni < 4; ++ni)
    qreg[ni] = Qphi[((b << 4) + h) * 64 + ni * 16 + l15];

  const int fsw = (l15 >> 1) & 3;              // read-side chunk XOR

  // prologue: stage chunk 0
  f32x4 p0 = *(const f32x4*)(Ab);
  f32x4 p1 = *(const f32x4*)(Ab + 4);
  gload_lds16(Bb,             &sB[0][wv * 1024]);
  gload_lds16(Bb + 16 * 1024, &sB[0][wv * 1024 + 512]);
  {
    bf16x8 v;
    v[0]=(short)f2bf(p0[0]); v[1]=(short)f2bf(p0[1]); v[2]=(short)f2bf(p0[2]); v[3]=(short)f2bf(p0[3]);
    v[4]=(short)f2bf(p1[0]); v[5]=(short)f2bf(p1[1]); v[6]=(short)f2bf(p1[2]); v[7]=(short)f2bf(p1[3]);
    *(bf16x8*)&sA[0][sAoff] = v;
  }
  __syncthreads();

  for (int t = 0; t < 32; ++t) {
    const int cur = t & 1, nxt = cur ^ 1;
    f32x4 a0, a1;
    if (t < 31) {                               // prefetch chunk t+1
      const float* An = Ab + (t + 1) * 32;
      a0 = *(const f32x4*)(An);
      a1 = *(const f32x4*)(An + 4);
      const unsigned short* Bn = Bb + (t + 1) * 32;
      gload_lds16(Bn,             &sB[nxt][wv * 1024]);
      gload_lds16(Bn + 16 * 1024, &sB[nxt][wv * 1024 + 512]);
    }
    bf16x8 af[4], bfr[4];
    #pragma unroll
    for (int mi = 0; mi < 4; ++mi)
      af[mi] = *(const bf16x8*)&sA[cur][((wr << 6) + mi * 16 + l15) * 40 + lk];
    #pragma unroll
    for (int ni = 0; ni < 4; ++ni)
      bfr[ni] = *(const bf16x8*)&sB[cur][((wc << 6) + ni * 16 + l15) * 32
                                         + ((((lane >> 4) ^ fsw)) << 3)];
    #pragma unroll
    for (int mi = 0; mi < 4; ++mi)
      #pragma unroll
      for (int ni = 0; ni < 4; ++ni)
        acc[mi][ni] = __builtin_amdgcn_mfma_f32_16x16x32_bf16(af[mi], bfr[ni], acc[mi][ni], 0, 0, 0);
    if (t < 31) {
      bf16x8 v;
      v[0]=(short)f2bf(a0[0]); v[1]=(short)f2bf(a0[1]); v[2]=(short)f2bf(a0[2]); v[3]=(short)f2bf(a0[3]);
      v[4]=(short)f2bf(a1[0]); v[5]=(short)f2bf(a1[1]); v[6]=(short)f2bf(a1[2]); v[7]=(short)f2bf(a1[3]);
      *(bf16x8*)&sA[nxt][sAoff] = v;
    }
    __syncthreads();
  }

  // epilogue: bias + phi + dot with Qphi -> w[b,h,t]
  float bias[4];
  #pragma unroll
  for (int ni = 0; ni < 4; ++ni) bias[ni] = bk[n0 + (wc << 6) + ni * 16 + l15];

  #pragma unroll
  for (int mi = 0; mi < 4; ++mi) {
    float wa[4];
    #pragma unroll
    for (int r = 0; r < 4; ++r) {
      float s = 0.f;
      #pragma unroll
      for (int ni = 0; ni < 4; ++ni) {
        float x = acc[mi][ni][r] + bias[ni];
        x = x > 0.f ? x + 1.f : __expf(x);     // phi
        s += x * qreg[ni];
      }
      wa[r] = s;
    }
    #pragma unroll
    for (int m = 1; m < 16; m <<= 1)
      #pragma unroll
      for (int r = 0; r < 4; ++r) wa[r] += __shfl_xor(wa[r], m, 64);
    if (l15 == 0) {
      const int rg = lane >> 4;
      #pragma unroll
      for (int r = 0; r < 4; ++r) {
        int trow = mrow + (wr << 6) + mi * 16 + (rg << 2) + r;
        w[(((size_t)((b << 4) + h)) << 13) + trow] = wa[r];
      }
    }
  }
}

// ---- S[b,h,:] = sum_t w * value_t  (fp32, streaming) --------------------
__global__ __launch_bounds__(256)
void k_sgemm(const float* __restrict__ value, const float* __restrict__ w,
             float* __restrict__ S) {
  __shared__ float wl[16 * 256];
  const int b = blockIdx.x, tc = blockIdx.y;   // 16 x 32
  const int t0 = tc << 8;
  const int tid = threadIdx.x;
  for (int i = tid; i < 16 * 256; i += 256)
    wl[i] = w[(((size_t)(b * 16 + (i >> 8))) << 13) + t0 + (i & 255)];
  __syncthreads();
  f32x4 acc[16];
  #pragma unroll
  for (int h = 0; h < 16; ++h) acc[h] = (f32x4)0.f;
  const f32x4* vb = (const f32x4*)(value + ((size_t)(b << 13) + t0) * 1024) + tid;
  #pragma unroll 4
  for (int t = 0; t < 256; ++t) {
    f32x4 x = vb[t << 8];
    #pragma unroll
    for (int h = 0; h < 16; ++h)
      acc[h] += x * wl[(h << 8) + t];
  }
  #pragma unroll
  for (int h = 0; h < 16; ++h) {
    float* sp = S + ((b << 4) + h) * 1024 + (tid << 2);
    atomicAdd(sp + 0, acc[h][0]); atomicAdd(sp + 1, acc[h][1]);
    atomicAdd(sp + 2, acc[h][2]); atomicAdd(sp + 3, acc[h][3]);
  }
}

// ---- den + num + divide --------------------------------------------------
__global__ void k_numden(const float* __restrict__ w, const float* __restrict__ S,
                         const float* __restrict__ Wv, const float* __restrict__ bv,
                         float* __restrict__ pre) {
  const int b = blockIdx.x, h = blockIdx.y, e = threadIdx.x;  // block = 64
  const float* wb = w + (((size_t)(b * 16 + h)) << 13);
  float dsum = 0.f;
  for (int i = 0; i < 128; ++i) dsum += wb[i * 64 + e];
  #pragma unroll
  for (int m = 1; m < 64; m <<= 1) dsum += __shfl_xor(dsum, m, 64);
  const f32x4* sr  = (const f32x4*)(S + (b * 16 + h) * 1024);
  const f32x4* wvr = (const f32x4*)(Wv + (size_t)(h * 64 + e) * 1024);
  float ns = 0.f;
  for (int i = 0; i < 256; ++i) {
    f32x4 a = sr[i], c = wvr[i];
    ns += a[0]*c[0] + a[1]*c[1] + a[2]*c[2] + a[3]*c[3];
  }
  ns += dsum * bv[h * 64 + e];
  pre[b * 1024 + h * 64 + e] = ns / (dsum + 1e-6f);
}

// ---- output projection ---------------------------------------------------
__global__ __launch_bounds__(256)
void k_outproj(const float* __restrict__ pre, const float* __restrict__ Wo,
               const float* __restrict__ bo, float* __restrict__ out) {
  __shared__ float pl[1024];
  const int b = blockIdx.x, ch = blockIdx.y;   // 16 x 4
  const int tid = threadIdx.x, lane = tid & 63, wv = tid >> 6;
  for (int i = tid; i < 1024; i += 256) pl[i] = pre[b * 1024 + i];
  __syncthreads();
  for (int oi = 0; oi < 64; ++oi) {
    int o = (ch << 8) + (wv << 6) + oi;
    const f32x4* wrow = (const f32x4*)(Wo + (size_t)o * 1024);
    float s = 0.f;
    #pragma unroll
    for (int j = 0; j < 4; ++j) {
      f32x4 v = wrow[lane * 4 + j];
      f32x4 p = *(const f32x4*)&pl[(lane * 4 + j) * 4];
      s += v[0]*p[0] + v[1]*p[1] + v[2]*p[2] + v[3]*p[3];
    }
    #pragma unroll
    for (int m = 1; m < 64; m <<= 1) s += __shfl_xor(s, m, 64);
    if (lane == 0) out[b * 1024 + o] = s + bo[o];
  }
}

extern "C" void kernel_launch(void* const* d_in, const int* in_sizes, int n_in,
                              void* d_out, int out_size, void* d_ws, size_t ws_size,
                              hipStream_t stream) {
  const float* query = (const float*)d_in[0];
  const float* key   = (const float*)d_in[1];
  const float* value = (const float*)d_in[2];
  const float* Wq    = (const float*)d_in[3];
  const float* bq    = (const float*)d_in[4];
  const float* Wk    = (const float*)d_in[5];
  const float* bk    = (const float*)d_in[6];
  const float* Wv    = (const float*)d_in[7];
  const float* bv    = (const float*)d_in[8];
  const float* Wo    = (const float*)d_in[9];
  const float* bo    = (const float*)d_in[10];
  float* out = (float*)d_out;
  char* ws = (char*)d_ws;
  float*          Qphi = (float*)(ws + WS_QPHI);
  float*          pre  = (float*)(ws + WS_PRE);
  float*          S    = (float*)(ws + WS_S);
  unsigned short* Wkb  = (unsigned short*)(ws + WS_WKB);
  float*          w    = (float*)(ws + WS_W);

  hipMemsetAsync(S, 0, 16 * 16 * 1024 * sizeof(float), stream);
  k_convert_wk<<<1024, 256, 0, stream>>>(Wk, Wkb);
  k_qproj<<<dim3(16, 16), 64, 0, stream>>>(query, Wq, bq, Qphi);
  k_kproj<<<dim3(4, 1024), 512, 0, stream>>>(key, Wkb, bk, Qphi, w);
  k_sgemm<<<dim3(16, 32), 256, 0, stream>>>(value, w, S);
  k_numden<<<dim3(16, 16), 64, 0, stream>>>(w, S, Wv, bv, pre);
  k_outproj<<<dim3(16, 4), 256, 0, stream>>>(pre, Wo, bo, out);
}

// Round 4
// 699.401 us; speedup vs baseline: 1.2772x; 1.0375x over previous
//
#include <hip/hip_runtime.h>

// LinearTrajectoryAttention, restructured:
//   Qphi = phi(query @ Wq^T + bq)                  [16][16][64]
//   w[b,h,t] = Qphi[b,h,:] . phi(key_t @ Wk^T + bk)[h]   (fused into K-proj epilogue)
//   den[b,h] = sum_t w ;  S[b,h,:] = sum_t w * value_t
//   pre[b,h*64+e] = (Wv[h*64+e,:].S + den*bv) / (den + 1e-6)
//   out = pre @ Wo^T + bo
// R4 kproj: ALL staging via global_load_lds (zero staging regs):
//   - A staged as fp32, 3-deep LDS buffers, chunk-XOR swizzle (c ^= row&7) via
//     pre-swizzled global source; converted to bf16 at ds_read time (cvt_pk).
//   - B staged bf16, 2-deep, R3's verified chunk-XOR path.
//   - per-step tail: s_waitcnt vmcnt(2) lgkmcnt(0); s_barrier.  B(t+1) issued
//     BEFORE A(t+2), so vmcnt(2) retires B(t+1) and leaves A(t+2) in flight
//     across the barrier (~2-step latency cover). lgkmcnt(0) is required:
//     step-t read buffers are exactly the step-t+1 DMA targets.
//   LDS = 3*16K (A) + 2*16K (B) = 81920 B -> 2 blocks/CU. VGPR+AGPR <= 128.

typedef __attribute__((ext_vector_type(8))) short  bf16x8;
typedef __attribute__((ext_vector_type(4))) short  bf16x4;
typedef __attribute__((ext_vector_type(4))) float  f32x4;

// workspace layout (bytes)
#define WS_QPHI 0u          // [16][16][64] f32      = 65536
#define WS_PRE  65536u      // [16][1024]  f32       = 65536
#define WS_S    131072u     // [16][16][1024] f32    = 1048576
#define WS_WKB  1179648u    // [1024][1024] bf16     = 2097152
#define WS_W    3276800u    // [16][16][8192] f32    = 8388608  (total ~11.7 MB)

__device__ __forceinline__ unsigned short f2bf(float f) {
  union { float f; unsigned u; } c; c.f = f;
  unsigned u = c.u;
  return (unsigned short)((u + 0x7fffu + ((u >> 16) & 1u)) >> 16);  // RNE
}

__device__ __forceinline__ unsigned cvt_pk_bf16(float lo, float hi) {
  unsigned r;
  asm("v_cvt_pk_bf16_f32 %0, %1, %2" : "=v"(r) : "v"(lo), "v"(hi));
  return r;
}

__device__ __forceinline__ void gload_lds16(const void* g, void* l) {
  __builtin_amdgcn_global_load_lds((const __attribute__((address_space(1))) void*)g,
                                   (__attribute__((address_space(3))) void*)l, 16, 0, 0);
}

// ---- Wk fp32 -> bf16 ----------------------------------------------------
__global__ void k_convert_wk(const float* __restrict__ Wk, unsigned short* __restrict__ Wkb) {
  int i = blockIdx.x * 256 + threadIdx.x;     // 262144 float4s
  f32x4 v = ((const f32x4*)Wk)[i];
  bf16x4 o;
  o[0] = (short)f2bf(v[0]); o[1] = (short)f2bf(v[1]);
  o[2] = (short)f2bf(v[2]); o[3] = (short)f2bf(v[3]);
  ((bf16x4*)Wkb)[i] = o;
}

// ---- Q projection + feature map ----------------------------------------
__global__ void k_qproj(const float* __restrict__ q, const float* __restrict__ Wq,
                        const float* __restrict__ bq, float* __restrict__ Qphi) {
  int b = blockIdx.x, h = blockIdx.y, d = threadIdx.x;  // block = 64
  const f32x4* qr = (const f32x4*)(q + b * 1024);
  const f32x4* wr = (const f32x4*)(Wq + (size_t)(h * 64 + d) * 1024);
  float s = bq[h * 64 + d];
  for (int i = 0; i < 256; ++i) {
    f32x4 a = qr[i], ww = wr[i];
    s += a[0]*ww[0] + a[1]*ww[1] + a[2]*ww[2] + a[3]*ww[3];
  }
  s = s > 0.f ? s + 1.f : __expf(s);  // elu(x)+1
  Qphi[(b * 16 + h) * 64 + d] = s;
}

// ---- K projection GEMM (BM=128, BN=256=4 heads, BK=32) + fused w epilogue
__global__ __launch_bounds__(512, 4)
void k_kproj(const float* __restrict__ key, const unsigned short* __restrict__ Wkb,
             const float* __restrict__ bk, const float* __restrict__ Qphi,
             float* __restrict__ w) {
  __shared__ float          sAf[3][128 * 32];  // 48 KB fp32 A, chunk-XOR (c^row&7)
  __shared__ unsigned short sB [2][256 * 32];  // 32 KB bf16 B, chunk-XOR (R3 path)

  // XCD-bijective swizzle (R2/R3-verified): 4 np-sharers of each mb same XCD.
  const int bid  = blockIdx.x + (blockIdx.y << 2);          // 0..4095
  const int work = ((bid & 7) << 9) | (bid >> 3);           // xcd*512 + idx
  const int np   = work & 3;
  const int mb   = work >> 2;
  const int b    = mb >> 6;
  const int mrow = (mb & 63) << 7;
  const int tid  = threadIdx.x;
  const int lane = tid & 63;
  const int wv   = tid >> 6;                   // 8 waves, 2 (rows) x 4 (cols)
  const int wr   = wv >> 2;
  const int wc   = wv & 3;
  const int n0   = np << 8;
  const int h    = (np << 2) | wc;             // this wave's head
  const int l15  = lane & 15;

  // A fragment read geometry: f32 cols kc..kc+7, chunks c0,c0+1 (4 f32 each)
  const int c0    = (lane >> 4) << 1;          // 0,2,4,6
  const int rx7   = l15 & 7;                   // == row&7 for all frags
  const int cAoff = ((c0 ^ rx7) << 2);
  const int cBoff = (((c0 + 1) ^ rx7) << 2);

  // A DMA source (per lane): dest row R = wv*16 + j*8 + (lane>>3), chunk lane&7;
  // content = global (R, (lane&7) ^ (R&7)); (R&7) == (lane>>3)&7 since bases %8==0.
  const int Rr0 = (wv << 4) + (lane >> 3);
  const int asw = ((lane & 7) ^ ((lane >> 3) & 7)) << 2;    // f32 offset
  const float* PA0 = key + (size_t)((b << 13) + mrow + Rr0) * 1024 + asw;

  // B DMA source (verbatim R3, verified)
  const int bsw = ((lane & 3) ^ ((lane >> 3) & 3)) << 3;    // shorts
  const unsigned short* Bb = Wkb + ((size_t)(n0 + (wv << 5) + (lane >> 2))) * 1024 + bsw;
  const int fsw = (l15 >> 1) & 3;              // B read-side chunk XOR

  f32x4 acc[4][4];
  #pragma unroll
  for (int i = 0; i < 4; ++i)
    #pragma unroll
    for (int j = 0; j < 4; ++j) acc[i][j] = (f32x4)0.f;

  float qreg[4];
  #pragma unroll
  for (int ni = 0; ni < 4; ++ni)
    qreg[ni] = Qphi[((b << 4) + h) * 64 + ni * 16 + l15];

  // ---- prologue: B(0)->sB[0]; A(0)->sAf[0]; A(1)->sAf[1]  (B first!)
  gload_lds16(Bb,             &sB[0][wv * 1024]);
  gload_lds16(Bb + 16 * 1024, &sB[0][wv * 1024 + 512]);
  gload_lds16(PA0,            &sAf[0][(wv << 9)]);
  gload_lds16(PA0 + 8 * 1024, &sAf[0][(wv << 9) + 256]);
  gload_lds16(PA0 + 32,            &sAf[1][(wv << 9)]);
  gload_lds16(PA0 + 8 * 1024 + 32, &sAf[1][(wv << 9) + 256]);
  asm volatile("s_waitcnt vmcnt(2)" ::: "memory");   // B(0),A(0) done; A(1) flying
  __builtin_amdgcn_s_barrier();

  int aCur = 0;
  #pragma unroll 1
  for (int t = 0; t < 32; ++t) {
    const int aN2 = (aCur >= 1) ? (aCur - 1) : 2;    // (aCur+2)%3
    // issue B(t+1) FIRST, then A(t+2)
    if (t < 31) {
      const unsigned short* Bn = Bb + (t + 1) * 32;
      gload_lds16(Bn,             &sB[(t + 1) & 1][wv * 1024]);
      gload_lds16(Bn + 16 * 1024, &sB[(t + 1) & 1][wv * 1024 + 512]);
    }
    if (t < 30) {
      const float* An = PA0 + (t + 2) * 32;
      gload_lds16(An,             &sAf[aN2][(wv << 9)]);
      gload_lds16(An + 8 * 1024,  &sAf[aN2][(wv << 9) + 256]);
    }
    // compute on buffers t
    {
      const float*          pA = &sAf[aCur][0];
      const unsigned short* pB = &sB[t & 1][0];
      bf16x8 bfr[4];
      #pragma unroll
      for (int ni = 0; ni < 4; ++ni)
        bfr[ni] = *(const bf16x8*)&pB[((wc << 6) + ni * 16 + l15) * 32
                                      + (((lane >> 4) ^ fsw) << 3)];
      #pragma unroll
      for (int mi = 0; mi < 4; ++mi) {
        const int rbase = ((wr << 6) + mi * 16 + l15) * 32;
        f32x4 ca = *(const f32x4*)&pA[rbase + cAoff];
        f32x4 cb = *(const f32x4*)&pA[rbase + cBoff];
        union { bf16x8 v; unsigned u[4]; } af;
        af.u[0] = cvt_pk_bf16(ca[0], ca[1]); af.u[1] = cvt_pk_bf16(ca[2], ca[3]);
        af.u[2] = cvt_pk_bf16(cb[0], cb[1]); af.u[3] = cvt_pk_bf16(cb[2], cb[3]);
        #pragma unroll
        for (int ni = 0; ni < 4; ++ni)
          acc[mi][ni] = __builtin_amdgcn_mfma_f32_16x16x32_bf16(af.v, bfr[ni], acc[mi][ni], 0, 0, 0);
      }
    }
    if (t < 31) {
      if (t < 30) asm volatile("s_waitcnt vmcnt(2) lgkmcnt(0)" ::: "memory");
      else        asm volatile("s_waitcnt vmcnt(0) lgkmcnt(0)" ::: "memory");
      __builtin_amdgcn_s_barrier();
    }
    aCur = (aCur == 2) ? 0 : aCur + 1;
  }

  // epilogue: bias + phi + dot with Qphi -> w[b,h,t]
  float bias[4];
  #pragma unroll
  for (int ni = 0; ni < 4; ++ni) bias[ni] = bk[n0 + (wc << 6) + ni * 16 + l15];

  #pragma unroll
  for (int mi = 0; mi < 4; ++mi) {
    float wa[4];
    #pragma unroll
    for (int r = 0; r < 4; ++r) {
      float s = 0.f;
      #pragma unroll
      for (int ni = 0; ni < 4; ++ni) {
        float x = acc[mi][ni][r] + bias[ni];
        x = x > 0.f ? x + 1.f : __expf(x);     // phi
        s += x * qreg[ni];
      }
      wa[r] = s;
    }
    #pragma unroll
    for (int m = 1; m < 16; m <<= 1)
      #pragma unroll
      for (int r = 0; r < 4; ++r) wa[r] += __shfl_xor(wa[r], m, 64);
    if (l15 == 0) {
      const int rg = lane >> 4;
      #pragma unroll
      for (int r = 0; r < 4; ++r) {
        int trow = mrow + (wr << 6) + mi * 16 + (rg << 2) + r;
        w[(((size_t)((b << 4) + h)) << 13) + trow] = wa[r];
      }
    }
  }
}

// ---- S[b,h,:] = sum_t w * value_t  (fp32, streaming) --------------------
__global__ __launch_bounds__(256)
void k_sgemm(const float* __restrict__ value, const float* __restrict__ w,
             float* __restrict__ S) {
  __shared__ float wl[16 * 256];
  const int b = blockIdx.x, tc = blockIdx.y;   // 16 x 32
  const int t0 = tc << 8;
  const int tid = threadIdx.x;
  for (int i = tid; i < 16 * 256; i += 256)
    wl[i] = w[(((size_t)(b * 16 + (i >> 8))) << 13) + t0 + (i & 255)];
  __syncthreads();
  f32x4 acc[16];
  #pragma unroll
  for (int h = 0; h < 16; ++h) acc[h] = (f32x4)0.f;
  const f32x4* vb = (const f32x4*)(value + ((size_t)(b << 13) + t0) * 1024) + tid;
  #pragma unroll 4
  for (int t = 0; t < 256; ++t) {
    f32x4 x = vb[t << 8];
    #pragma unroll
    for (int h = 0; h < 16; ++h)
      acc[h] += x * wl[(h << 8) + t];
  }
  #pragma unroll
  for (int h = 0; h < 16; ++h) {
    float* sp = S + ((b << 4) + h) * 1024 + (tid << 2);
    atomicAdd(sp + 0, acc[h][0]); atomicAdd(sp + 1, acc[h][1]);
    atomicAdd(sp + 2, acc[h][2]); atomicAdd(sp + 3, acc[h][3]);
  }
}

// ---- den + num + divide --------------------------------------------------
__global__ void k_numden(const float* __restrict__ w, const float* __restrict__ S,
                         const float* __restrict__ Wv, const float* __restrict__ bv,
                         float* __restrict__ pre) {
  const int b = blockIdx.x, h = blockIdx.y, e = threadIdx.x;  // block = 64
  const float* wb = w + (((size_t)(b * 16 + h)) << 13);
  float dsum = 0.f;
  for (int i = 0; i < 128; ++i) dsum += wb[i * 64 + e];
  #pragma unroll
  for (int m = 1; m < 64; m <<= 1) dsum += __shfl_xor(dsum, m, 64);
  const f32x4* sr  = (const f32x4*)(S + (b * 16 + h) * 1024);
  const f32x4* wvr = (const f32x4*)(Wv + (size_t)(h * 64 + e) * 1024);
  float ns = 0.f;
  for (int i = 0; i < 256; ++i) {
    f32x4 a = sr[i], c = wvr[i];
    ns += a[0]*c[0] + a[1]*c[1] + a[2]*c[2] + a[3]*c[3];
  }
  ns += dsum * bv[h * 64 + e];
  pre[b * 1024 + h * 64 + e] = ns / (dsum + 1e-6f);
}

// ---- output projection ---------------------------------------------------
__global__ __launch_bounds__(256)
void k_outproj(const float* __restrict__ pre, const float* __restrict__ Wo,
               const float* __restrict__ bo, float* __restrict__ out) {
  __shared__ float pl[1024];
  const int b = blockIdx.x, ch = blockIdx.y;   // 16 x 4
  const int tid = threadIdx.x, lane = tid & 63, wv = tid >> 6;
  for (int i = tid; i < 1024; i += 256) pl[i] = pre[b * 1024 + i];
  __syncthreads();
  for (int oi = 0; oi < 64; ++oi) {
    int o = (ch << 8) + (wv << 6) + oi;
    const f32x4* wrow = (const f32x4*)(Wo + (size_t)o * 1024);
    float s = 0.f;
    #pragma unroll
    for (int j = 0; j < 4; ++j) {
      f32x4 v = wrow[lane * 4 + j];
      f32x4 p = *(const f32x4*)&pl[(lane * 4 + j) * 4];
      s += v[0]*p[0] + v[1]*p[1] + v[2]*p[2] + v[3]*p[3];
    }
    #pragma unroll
    for (int m = 1; m < 64; m <<= 1) s += __shfl_xor(s, m, 64);
    if (lane == 0) out[b * 1024 + o] = s + bo[o];
  }
}

extern "C" void kernel_launch(void* const* d_in, const int* in_sizes, int n_in,
                              void* d_out, int out_size, void* d_ws, size_t ws_size,
                              hipStream_t stream) {
  const float* query = (const float*)d_in[0];
  const float* key   = (const float*)d_in[1];
  const float* value = (const float*)d_in[2];
  const float* Wq    = (const float*)d_in[3];
  const float* bq    = (const float*)d_in[4];
  const float* Wk    = (const float*)d_in[5];
  const float* bk    = (const float*)d_in[6];
  const float* Wv    = (const float*)d_in[7];
  const float* bv    = (const float*)d_in[8];
  const float* Wo    = (const float*)d_in[9];
  const float* bo    = (const float*)d_in[10];
  float* out = (float*)d_out;
  char* ws = (char*)d_ws;
  float*          Qphi = (float*)(ws + WS_QPHI);
  float*          pre  = (float*)(ws + WS_PRE);
  float*          S    = (float*)(ws + WS_S);
  unsigned short* Wkb  = (unsigned short*)(ws + WS_WKB);
  float*          w    = (float*)(ws + WS_W);

  hipMemsetAsync(S, 0, 16 * 16 * 1024 * sizeof(float), stream);
  k_convert_wk<<<1024, 256, 0, stream>>>(Wk, Wkb);
  k_qproj<<<dim3(16, 16), 64, 0, stream>>>(query, Wq, bq, Qphi);
  k_kproj<<<dim3(4, 1024), 512, 0, stream>>>(key, Wkb, bk, Qphi, w);
  k_sgemm<<<dim3(16, 32), 256, 0, stream>>>(value, w, S);
  k_numden<<<dim3(16, 16), 64, 0, stream>>>(w, S, Wv, bv, pre);
  k_outproj<<<dim3(16, 4), 256, 0, stream>>>(pre, Wo, bo, out);
}

// Round 5
// 653.143 us; speedup vs baseline: 1.3677x; 1.0708x over previous
//
#include <hip/hip_runtime.h>

// LinearTrajectoryAttention, restructured:
//   Qphi = phi(query @ Wq^T + bq)                  [16][16][64]
//   w[b,h,t] = Qphi[b,h,:] . phi(key_t @ Wk^T + bk)[h]   (fused into K-proj epilogue)
//   den[b,h] = sum_t w ;  S[b,h,:] = sum_t w * value_t
//   pre[b,h*64+e] = (Wv[h*64+e,:].S + den*bv) / (den + 1e-6)
//   out = pre @ Wo^T + bo
// R5 kproj: bf16-A reg-staged (cvt at WRITE side, pitch-40 conflict-free reads,
//   8 b128/wave/step LDS floor ~165us) + counted-vmcnt pipeline:
//   - A: global f32x4 x2 issued at step top for t+1 (pinned first via
//     sched_barrier), cvt_pk x4, ds_write_b128 into 2-deep pitch-40 buffers.
//   - B: DMA 3-deep (R3-verified chunk-XOR source/read); B(t+2) issued per
//     step AFTER A's loads -> compiler's A-register-wait is vmcnt(2): retires
//     B(t+1)+A, leaves B(t+2) in flight ACROSS the barrier (~2-step cover).
//   - tail: s_waitcnt vmcnt(2) lgkmcnt(0); raw s_barrier; sched_barrier(0).
//   LDS = 2*10240(A) + 3*16384(B) = 69632 B -> 2 blocks/CU. VGPR+AGPR <= 128.

typedef __attribute__((ext_vector_type(8))) short  bf16x8;
typedef __attribute__((ext_vector_type(4))) short  bf16x4;
typedef __attribute__((ext_vector_type(4))) float  f32x4;

// workspace layout (bytes)
#define WS_QPHI 0u          // [16][16][64] f32      = 65536
#define WS_PRE  65536u      // [16][1024]  f32       = 65536
#define WS_S    131072u     // [16][16][1024] f32    = 1048576
#define WS_WKB  1179648u    // [1024][1024] bf16     = 2097152
#define WS_W    3276800u    // [16][16][8192] f32    = 8388608  (total ~11.7 MB)

__device__ __forceinline__ unsigned short f2bf(float f) {
  union { float f; unsigned u; } c; c.f = f;
  unsigned u = c.u;
  return (unsigned short)((u + 0x7fffu + ((u >> 16) & 1u)) >> 16);  // RNE
}

__device__ __forceinline__ unsigned cvt_pk_bf16(float lo, float hi) {
  unsigned r;
  asm("v_cvt_pk_bf16_f32 %0, %1, %2" : "=v"(r) : "v"(lo), "v"(hi));
  return r;
}

__device__ __forceinline__ uint4 pack_bf16x8(f32x4 x, f32x4 y) {
  uint4 r;
  r.x = cvt_pk_bf16(x[0], x[1]); r.y = cvt_pk_bf16(x[2], x[3]);
  r.z = cvt_pk_bf16(y[0], y[1]); r.w = cvt_pk_bf16(y[2], y[3]);
  return r;
}

__device__ __forceinline__ void gload_lds16(const void* g, void* l) {
  __builtin_amdgcn_global_load_lds((const __attribute__((address_space(1))) void*)g,
                                   (__attribute__((address_space(3))) void*)l, 16, 0, 0);
}

// ---- Wk fp32 -> bf16 ----------------------------------------------------
__global__ void k_convert_wk(const float* __restrict__ Wk, unsigned short* __restrict__ Wkb) {
  int i = blockIdx.x * 256 + threadIdx.x;     // 262144 float4s
  f32x4 v = ((const f32x4*)Wk)[i];
  bf16x4 o;
  o[0] = (short)f2bf(v[0]); o[1] = (short)f2bf(v[1]);
  o[2] = (short)f2bf(v[2]); o[3] = (short)f2bf(v[3]);
  ((bf16x4*)Wkb)[i] = o;
}

// ---- Q projection + feature map ----------------------------------------
__global__ void k_qproj(const float* __restrict__ q, const float* __restrict__ Wq,
                        const float* __restrict__ bq, float* __restrict__ Qphi) {
  int b = blockIdx.x, h = blockIdx.y, d = threadIdx.x;  // block = 64
  const f32x4* qr = (const f32x4*)(q + b * 1024);
  const f32x4* wr = (const f32x4*)(Wq + (size_t)(h * 64 + d) * 1024);
  float s = bq[h * 64 + d];
  for (int i = 0; i < 256; ++i) {
    f32x4 a = qr[i], ww = wr[i];
    s += a[0]*ww[0] + a[1]*ww[1] + a[2]*ww[2] + a[3]*ww[3];
  }
  s = s > 0.f ? s + 1.f : __expf(s);  // elu(x)+1
  Qphi[(b * 16 + h) * 64 + d] = s;
}

// ---- K projection GEMM (BM=128, BN=256=4 heads, BK=32) + fused w epilogue
__global__ __launch_bounds__(512, 4)
void k_kproj(const float* __restrict__ key, const unsigned short* __restrict__ Wkb,
             const float* __restrict__ bk, const float* __restrict__ Qphi,
             float* __restrict__ w) {
  __shared__ __align__(16) unsigned short sA[2][128 * 40];  // 20480 B, pitch-40
  __shared__ __align__(16) unsigned short sB[3][256 * 32];  // 49152 B, chunk-XOR

  // XCD-bijective swizzle (R2/R3-verified): 4 np-sharers of each mb same XCD.
  const int bid  = blockIdx.x + (blockIdx.y << 2);          // 0..4095
  const int work = ((bid & 7) << 9) | (bid >> 3);           // xcd*512 + idx
  const int np   = work & 3;
  const int mb   = work >> 2;
  const int b    = mb >> 6;
  const int mrow = (mb & 63) << 7;
  const int tid  = threadIdx.x;
  const int lane = tid & 63;
  const int wv   = tid >> 6;                   // 8 waves, 2 (rows) x 4 (cols)
  const int wr   = wv >> 2;
  const int wc   = wv & 3;
  const int n0   = np << 8;
  const int h    = (np << 2) | wc;             // this wave's head
  const int l15  = lane & 15;
  const int lk   = (lane >> 4) << 3;           // k-offset 0,8,16,24 shorts (sA)

  // A staging map: thread -> (row = tid/4, 8 floats at col (tid&3)*8)
  const int ar = tid >> 2, aq = tid & 3;
  const float* Ab = key + ((size_t)((b << 13) + mrow + ar)) * 1024 + aq * 8;
  const int sAoff = ar * 40 + aq * 8;

  // B DMA source (verbatim R3, verified)
  const int bsw = ((lane & 3) ^ ((lane >> 3) & 3)) << 3;    // shorts
  const unsigned short* Bb = Wkb + ((size_t)(n0 + (wv << 5) + (lane >> 2))) * 1024 + bsw;
  const int fsw = (l15 >> 1) & 3;              // B read-side chunk XOR

  f32x4 acc[4][4];
  #pragma unroll
  for (int i = 0; i < 4; ++i)
    #pragma unroll
    for (int j = 0; j < 4; ++j) acc[i][j] = (f32x4)0.f;

  float qreg[4];
  #pragma unroll
  for (int ni = 0; ni < 4; ++ni)
    qreg[ni] = Qphi[((b << 4) + h) * 64 + ni * 16 + l15];

  // ---- prologue: A(0) regloads FIRST, then B(0),B(1) DMA; cvt+write A(0)
  f32x4 a0 = *(const f32x4*)(Ab);
  f32x4 a1 = *(const f32x4*)(Ab + 4);
  __builtin_amdgcn_sched_barrier(0);
  gload_lds16(Bb,                  &sB[0][wv * 1024]);
  gload_lds16(Bb + 16 * 1024,      &sB[0][wv * 1024 + 512]);
  gload_lds16(Bb + 32,             &sB[1][wv * 1024]);
  gload_lds16(Bb + 16 * 1024 + 32, &sB[1][wv * 1024 + 512]);
  __builtin_amdgcn_sched_barrier(0);
  *(uint4*)&sA[0][sAoff] = pack_bf16x8(a0, a1);   // compiler waits A only
  asm volatile("s_waitcnt vmcnt(2) lgkmcnt(0)" ::: "memory");  // B(0) done
  __builtin_amdgcn_s_barrier();
  __builtin_amdgcn_sched_barrier(0);

  #pragma unroll 1
  for (int t = 0; t < 32; ++t) {
    // 1) A regloads for tile t+1 (pinned first)
    if (t < 31) {
      const float* An = Ab + (t + 1) * 32;
      a0 = *(const f32x4*)(An);
      a1 = *(const f32x4*)(An + 4);
    }
    __builtin_amdgcn_sched_barrier(0);
    // 2) B DMA for tile t+2
    if (t < 30) {
      const unsigned short* Bn = Bb + (t + 2) * 32;
      const int bn = (t + 2) % 3;
      gload_lds16(Bn,             &sB[bn][wv * 1024]);
      gload_lds16(Bn + 16 * 1024, &sB[bn][wv * 1024 + 512]);
    }
    __builtin_amdgcn_sched_barrier(0);
    // 3) compute on sA[t&1], sB[t%3]
    {
      const unsigned short* pA = &sA[t & 1][0];
      const unsigned short* pB = &sB[t % 3][0];
      bf16x8 af[4], bfr[4];
      #pragma unroll
      for (int mi = 0; mi < 4; ++mi)
        af[mi] = *(const bf16x8*)&pA[((wr << 6) + mi * 16 + l15) * 40 + lk];
      #pragma unroll
      for (int ni = 0; ni < 4; ++ni)
        bfr[ni] = *(const bf16x8*)&pB[((wc << 6) + ni * 16 + l15) * 32
                                      + (((lane >> 4) ^ fsw) << 3)];
      #pragma unroll
      for (int mi = 0; mi < 4; ++mi)
        #pragma unroll
        for (int ni = 0; ni < 4; ++ni)
          acc[mi][ni] = __builtin_amdgcn_mfma_f32_16x16x32_bf16(af[mi], bfr[ni], acc[mi][ni], 0, 0, 0);
    }
    // 4) cvt + ds_write A tile t+1 (compiler's A-wait = vmcnt(2): B(t+2) flies)
    if (t < 31)
      *(uint4*)&sA[(t + 1) & 1][sAoff] = pack_bf16x8(a0, a1);
    // 5) tail
    if (t < 30)      asm volatile("s_waitcnt vmcnt(2) lgkmcnt(0)" ::: "memory");
    else if (t < 31) asm volatile("s_waitcnt vmcnt(0) lgkmcnt(0)" ::: "memory");
    if (t < 31) {
      __builtin_amdgcn_s_barrier();
      __builtin_amdgcn_sched_barrier(0);
    }
  }

  // epilogue: bias + phi + dot with Qphi -> w[b,h,t]
  float bias[4];
  #pragma unroll
  for (int ni = 0; ni < 4; ++ni) bias[ni] = bk[n0 + (wc << 6) + ni * 16 + l15];

  #pragma unroll
  for (int mi = 0; mi < 4; ++mi) {
    float wa[4];
    #pragma unroll
    for (int r = 0; r < 4; ++r) {
      float s = 0.f;
      #pragma unroll
      for (int ni = 0; ni < 4; ++ni) {
        float x = acc[mi][ni][r] + bias[ni];
        x = x > 0.f ? x + 1.f : __expf(x);     // phi
        s += x * qreg[ni];
      }
      wa[r] = s;
    }
    #pragma unroll
    for (int m = 1; m < 16; m <<= 1)
      #pragma unroll
      for (int r = 0; r < 4; ++r) wa[r] += __shfl_xor(wa[r], m, 64);
    if (l15 == 0) {
      const int rg = lane >> 4;
      #pragma unroll
      for (int r = 0; r < 4; ++r) {
        int trow = mrow + (wr << 6) + mi * 16 + (rg << 2) + r;
        w[(((size_t)((b << 4) + h)) << 13) + trow] = wa[r];
      }
    }
  }
}

// ---- S[b,h,:] = sum_t w * value_t  (fp32, streaming) --------------------
__global__ __launch_bounds__(256)
void k_sgemm(const float* __restrict__ value, const float* __restrict__ w,
             float* __restrict__ S) {
  __shared__ float wl[16 * 256];
  const int b = blockIdx.x, tc = blockIdx.y;   // 16 x 32
  const int t0 = tc << 8;
  const int tid = threadIdx.x;
  for (int i = tid; i < 16 * 256; i += 256)
    wl[i] = w[(((size_t)(b * 16 + (i >> 8))) << 13) + t0 + (i & 255)];
  __syncthreads();
  f32x4 acc[16];
  #pragma unroll
  for (int h = 0; h < 16; ++h) acc[h] = (f32x4)0.f;
  const f32x4* vb = (const f32x4*)(value + ((size_t)(b << 13) + t0) * 1024) + tid;
  #pragma unroll 4
  for (int t = 0; t < 256; ++t) {
    f32x4 x = vb[t << 8];
    #pragma unroll
    for (int h = 0; h < 16; ++h)
      acc[h] += x * wl[(h << 8) + t];
  }
  #pragma unroll
  for (int h = 0; h < 16; ++h) {
    float* sp = S + ((b << 4) + h) * 1024 + (tid << 2);
    atomicAdd(sp + 0, acc[h][0]); atomicAdd(sp + 1, acc[h][1]);
    atomicAdd(sp + 2, acc[h][2]); atomicAdd(sp + 3, acc[h][3]);
  }
}

// ---- den + num + divide (256 threads: 4 partial waves + LDS combine) ----
__global__ __launch_bounds__(256)
void k_numden(const float* __restrict__ w, const float* __restrict__ S,
              const float* __restrict__ Wv, const float* __restrict__ bv,
              float* __restrict__ pre) {
  __shared__ float red[2][4][64];
  const int b = blockIdx.x, h = blockIdx.y;
  const int tid = threadIdx.x, e = tid & 63, part = tid >> 6;
  const float* wb = w + (((size_t)(b * 16 + h)) << 13);
  float dsum = 0.f;
  for (int i = part * 32; i < part * 32 + 32; ++i) dsum += wb[i * 64 + e];
  const f32x4* sr  = (const f32x4*)(S + (b * 16 + h) * 1024);
  const f32x4* wvr = (const f32x4*)(Wv + (size_t)(h * 64 + e) * 1024);
  float ns = 0.f;
  for (int i = part * 64; i < part * 64 + 64; ++i) {
    f32x4 a = sr[i], c = wvr[i];
    ns += a[0]*c[0] + a[1]*c[1] + a[2]*c[2] + a[3]*c[3];
  }
  red[0][part][e] = dsum; red[1][part][e] = ns;
  __syncthreads();
  if (part == 0) {
    float d = red[0][0][e] + red[0][1][e] + red[0][2][e] + red[0][3][e];
    float n = red[1][0][e] + red[1][1][e] + red[1][2][e] + red[1][3][e];
    #pragma unroll
    for (int m = 1; m < 64; m <<= 1) d += __shfl_xor(d, m, 64);  // full den
    n += d * bv[h * 64 + e];
    pre[b * 1024 + h * 64 + e] = n / (d + 1e-6f);
  }
}

// ---- output projection ---------------------------------------------------
__global__ __launch_bounds__(256)
void k_outproj(const float* __restrict__ pre, const float* __restrict__ Wo,
               const float* __restrict__ bo, float* __restrict__ out) {
  __shared__ float pl[1024];
  const int b = blockIdx.x, ch = blockIdx.y;   // 16 x 8
  const int tid = threadIdx.x, lane = tid & 63, wv = tid >> 6;
  for (int i = tid; i < 1024; i += 256) pl[i] = pre[b * 1024 + i];
  __syncthreads();
  for (int oi = 0; oi < 32; ++oi) {
    int o = (ch << 7) + (wv << 5) + oi;
    const f32x4* wrow = (const f32x4*)(Wo + (size_t)o * 1024);
    float s = 0.f;
    #pragma unroll
    for (int j = 0; j < 4; ++j) {
      f32x4 v = wrow[lane * 4 + j];
      f32x4 p = *(const f32x4*)&pl[(lane * 4 + j) * 4];
      s += v[0]*p[0] + v[1]*p[1] + v[2]*p[2] + v[3]*p[3];
    }
    #pragma unroll
    for (int m = 1; m < 64; m <<= 1) s += __shfl_xor(s, m, 64);
    if (lane == 0) out[b * 1024 + o] = s + bo[o];
  }
}

extern "C" void kernel_launch(void* const* d_in, const int* in_sizes, int n_in,
                              void* d_out, int out_size, void* d_ws, size_t ws_size,
                              hipStream_t stream) {
  const float* query = (const float*)d_in[0];
  const float* key   = (const float*)d_in[1];
  const float* value = (const float*)d_in[2];
  const float* Wq    = (const float*)d_in[3];
  const float* bq    = (const float*)d_in[4];
  const float* Wk    = (const float*)d_in[5];
  const float* bk    = (const float*)d_in[6];
  const float* Wv    = (const float*)d_in[7];
  const float* bv    = (const float*)d_in[8];
  const float* Wo    = (const float*)d_in[9];
  const float* bo    = (const float*)d_in[10];
  float* out = (float*)d_out;
  char* ws = (char*)d_ws;
  float*          Qphi = (float*)(ws + WS_QPHI);
  float*          pre  = (float*)(ws + WS_PRE);
  float*          S    = (float*)(ws + WS_S);
  unsigned short* Wkb  = (unsigned short*)(ws + WS_WKB);
  float*          w    = (float*)(ws + WS_W);

  hipMemsetAsync(S, 0, 16 * 16 * 1024 * sizeof(float), stream);
  k_convert_wk<<<1024, 256, 0, stream>>>(Wk, Wkb);
  k_qproj<<<dim3(16, 16), 64, 0, stream>>>(query, Wq, bq, Qphi);
  k_kproj<<<dim3(4, 1024), 512, 0, stream>>>(key, Wkb, bk, Qphi, w);
  k_sgemm<<<dim3(16, 32), 256, 0, stream>>>(value, w, S);
  k_numden<<<dim3(16, 16), 256, 0, stream>>>(w, S, Wv, bv, pre);
  k_outproj<<<dim3(16, 8), 256, 0, stream>>>(pre, Wo, bo, out);
}